// Round 1
// baseline (521.475 us; speedup 1.0000x reference)
//
#include <hip/hip_runtime.h>
#include <hip/hip_bf16.h>

#define EPSF 1e-8f

// Problem sizes (fixed by reference setup_inputs)
constexpr int Bn = 8, Sn = 2048, Dn = 1024, Hn = 1024;
constexpr int Mn = Bn * Sn;           // 16384 rows of X (flattened b,s)
constexpr int BM = 128, BN = 64, BK = 32;

typedef short s16x8 __attribute__((ext_vector_type(8)));
typedef float f32x4 __attribute__((ext_vector_type(4)));

__device__ __forceinline__ unsigned short f2bf(float x) {
    // round-to-nearest-even fp32 -> bf16
    unsigned u = __float_as_uint(x);
    u += 0x7FFFu + ((u >> 16) & 1u);
    return (unsigned short)(u >> 16);
}

// Fused 3-output GEMM: zf,zi,zh = X @ {Wf,Wi,Wh}^T ; epilogue computes
// log_ret -> lr_out (ws), new_info -> m_out (d_out).
__global__ __launch_bounds__(256) void gate_gemm(
    const float* __restrict__ X,
    const float* __restrict__ Wf, const float* __restrict__ bfp,
    const float* __restrict__ Wi, const float* __restrict__ bip,
    const float* __restrict__ Wh, const float* __restrict__ bhp,
    float* __restrict__ lr_out, float* __restrict__ m_out)
{
    __shared__ unsigned short Alds[BM * BK];      // 8 KB
    __shared__ unsigned short Blds[3][BN * BK];   // 12 KB

    const int tid  = threadIdx.x;
    const int lane = tid & 63;
    const int wid  = tid >> 6;
    const int wr   = wid >> 1;   // 0..1 -> 64-row half
    const int wc   = wid & 1;    // 0..1 -> 32-col half

    const int tn = blockIdx.x & 15;   // 1024/64 = 16 col tiles
    const int tm = blockIdx.x >> 4;   // 128 row tiles
    const int rowBase = tm * BM;
    const int colBase = tn * BN;

    f32x4 acc[3][4][2] = {};

    const float* Wg[3] = {Wf, Wi, Wh};

    for (int k0 = 0; k0 < Dn; k0 += BK) {
        // --- stage A tile: 128x32 fp32 -> bf16 (1024 float4 loads) ---
        #pragma unroll
        for (int i = 0; i < 4; ++i) {
            int li = tid + 256 * i;
            int r  = li >> 3;
            int c  = (li & 7) << 2;
            const float4 v = *(const float4*)(X + (size_t)(rowBase + r) * Dn + k0 + c);
            ushort4 hv;
            hv.x = f2bf(v.x); hv.y = f2bf(v.y); hv.z = f2bf(v.z); hv.w = f2bf(v.w);
            *(ushort4*)(&Alds[r * BK + c]) = hv;
        }
        // --- stage B tiles (3 mats, 64x32 each) ---
        #pragma unroll
        for (int g = 0; g < 3; ++g) {
            #pragma unroll
            for (int i = 0; i < 2; ++i) {
                int li = tid + 256 * i;
                int r  = li >> 3;
                int c  = (li & 7) << 2;
                const float4 v = *(const float4*)(Wg[g] + (size_t)(colBase + r) * Dn + k0 + c);
                ushort4 hv;
                hv.x = f2bf(v.x); hv.y = f2bf(v.y); hv.z = f2bf(v.z); hv.w = f2bf(v.w);
                *(ushort4*)(&Blds[g][r * BK + c]) = hv;
            }
        }
        __syncthreads();

        // --- fragments + MFMA ---
        const int kq  = (lane >> 4) << 3;   // 0,8,16,24 (8 contiguous k per lane)
        const int l16 = lane & 15;
        s16x8 af[4];
        #pragma unroll
        for (int mf = 0; mf < 4; ++mf) {
            int row = wr * 64 + mf * 16 + l16;
            af[mf] = *(const s16x8*)(&Alds[row * BK + kq]);
        }
        #pragma unroll
        for (int g = 0; g < 3; ++g) {
            s16x8 bfr[2];
            #pragma unroll
            for (int nf = 0; nf < 2; ++nf) {
                int col = wc * 32 + nf * 16 + l16;
                bfr[nf] = *(const s16x8*)(&Blds[g][col * BK + kq]);
            }
            #pragma unroll
            for (int mf = 0; mf < 4; ++mf)
                #pragma unroll
                for (int nf = 0; nf < 2; ++nf)
                    acc[g][mf][nf] = __builtin_amdgcn_mfma_f32_16x16x32_bf16(
                        af[mf], bfr[nf], acc[g][mf][nf], 0, 0, 0);
        }
        __syncthreads();
    }

    // --- epilogue: gate math, write log_ret and new_info ---
    const int l16   = lane & 15;
    const int rquad = (lane >> 4) * 4;
    #pragma unroll
    for (int mf = 0; mf < 4; ++mf) {
        #pragma unroll
        for (int nf = 0; nf < 2; ++nf) {
            int col = colBase + wc * 32 + nf * 16 + l16;
            float bfv = bfp[col], biv = bip[col], bhv = bhp[col];
            #pragma unroll
            for (int r = 0; r < 4; ++r) {
                int row = rowBase + wr * 64 + mf * 16 + rquad + r;
                float zf = acc[0][mf][nf][r] + bfv;
                float zi = acc[1][mf][nf][r] + biv;
                float zh = acc[2][mf][nf][r] + bhv;
                float fg = 1.f / (1.f + __expf(-zf));
                float ig = 1.f / (1.f + __expf(-zi));
                float gs = fg + ig + EPSF;
                float fn = fg / gs;
                float in_ = ig / gs;
                size_t idx = (size_t)row * Hn + col;
                lr_out[idx] = __logf(fn + EPSF);
                m_out[idx]  = in_ * zh;
            }
        }
    }
}

// Sequential scan per (b,h): hidden_t = sum_{u<=t} exp(Ltot - L_{u-1})*m_u + exp(L_t)*h0
// In-place on io (holds m on entry, hidden on exit).
__global__ __launch_bounds__(64) void scan_kernel(
    const float* __restrict__ lr, float* __restrict__ io,
    const float* __restrict__ h0)
{
    const int tid = blockIdx.x * 64 + threadIdx.x;   // 0..8191
    const int b  = tid >> 10;
    const int hh = tid & 1023;
    const float* lrp = lr + (size_t)b * Sn * Hn + hh;
    float*       iop = io + (size_t)b * Sn * Hn + hh;

    float Lt = 0.f;
    #pragma unroll 8
    for (int t = 0; t < Sn; ++t) Lt += lrp[(size_t)t * Hn];

    float L = 0.f, acc = 0.f;
    const float h0v = h0[tid];
    #pragma unroll 4
    for (int t = 0; t < Sn; ++t) {
        float mv = iop[(size_t)t * Hn];
        float lv = lrp[(size_t)t * Hn];
        acc += __expf(Lt - L) * mv;   // L here is L_{t-1} (L_{-1}=0)
        L += lv;
        iop[(size_t)t * Hn] = acc + __expf(L) * h0v;
    }
}

extern "C" void kernel_launch(void* const* d_in, const int* in_sizes, int n_in,
                              void* d_out, int out_size, void* d_ws, size_t ws_size,
                              hipStream_t stream)
{
    const float* X  = (const float*)d_in[0];
    const float* h0 = (const float*)d_in[1];
    const float* Wf = (const float*)d_in[2];
    const float* bf = (const float*)d_in[3];
    const float* Wi = (const float*)d_in[4];
    const float* bi = (const float*)d_in[5];
    const float* Wh = (const float*)d_in[6];
    const float* bh = (const float*)d_in[7];
    float* out = (float*)d_out;
    float* lr  = (float*)d_ws;   // 16384*1024*4 = 64 MB

    const int grid = (Mn / BM) * (Hn / BN);   // 2048 blocks
    gate_gemm<<<grid, 256, 0, stream>>>(X, Wf, bf, Wi, bi, Wh, bh, lr, out);
    scan_kernel<<<(Bn * Hn) / 64, 64, 0, stream>>>(lr, out, h0);
}

// Round 2
// 204.225 us; speedup vs baseline: 2.5534x; 2.5534x over previous
//
#include <hip/hip_runtime.h>
#include <hip/hip_bf16.h>

#define EPSF 1e-8f

// Problem sizes (fixed by reference setup_inputs)
constexpr int Bn = 8, Sn = 2048, Dn = 1024, Hn = 1024;
constexpr int Mn = Bn * Sn;          // 16384 rows of X
constexpr int CH = 128;              // scan chunk length
constexpr int NC = Sn / CH;          // 16 chunks

typedef short s16x8 __attribute__((ext_vector_type(8)));
typedef float f32x4 __attribute__((ext_vector_type(4)));

__device__ __forceinline__ unsigned short f2bf(float x) {
    unsigned u = __float_as_uint(x);
    u += 0x7FFFu + ((u >> 16) & 1u);
    return (unsigned short)(u >> 16);
}

#define GLOAD_LDS16(gaddr, laddr)                                              \
    __builtin_amdgcn_global_load_lds(                                          \
        (const __attribute__((address_space(1))) void*)(gaddr),                \
        (__attribute__((address_space(3))) void*)(laddr), 16, 0, 0)

// ---------------------------------------------------------------------------
// fp32 -> bf16 convert (8 floats / thread)
// ---------------------------------------------------------------------------
__global__ __launch_bounds__(256) void cvt_bf16(const float* __restrict__ src,
                                                unsigned short* __restrict__ dst,
                                                int n8)
{
    int g = blockIdx.x * 256 + threadIdx.x;
    if (g >= n8) return;
    const float4* s4 = (const float4*)src;
    float4 a = s4[g * 2], b = s4[g * 2 + 1];
    ushort4 lo, hi;
    lo.x = f2bf(a.x); lo.y = f2bf(a.y); lo.z = f2bf(a.z); lo.w = f2bf(a.w);
    hi.x = f2bf(b.x); hi.y = f2bf(b.y); hi.z = f2bf(b.z); hi.w = f2bf(b.w);
    ((ushort4*)dst)[g * 2]     = lo;
    ((ushort4*)dst)[g * 2 + 1] = hi;
}

// ---------------------------------------------------------------------------
// FAST GEMM: bf16 inputs, global_load_lds staging, XOR-swizzled LDS.
// 3-output fused: lr_out = log(forget_norm+EPS), m_out = input_norm*candidate
// ---------------------------------------------------------------------------
__global__ __launch_bounds__(256) void gate_gemm_bf(
    const unsigned short* __restrict__ Xb,
    const unsigned short* __restrict__ Wb,   // [3][Hn][Dn] bf16 concat
    const float* __restrict__ bfp, const float* __restrict__ bip,
    const float* __restrict__ bhp,
    float* __restrict__ lr_out, float* __restrict__ m_out)
{
    constexpr int BM = 128, BN = 64, BK = 64;
    __shared__ unsigned short Alds[BM * BK];       // 16 KB
    __shared__ unsigned short Blds[3 * BN * BK];   // 24 KB

    const int tid  = threadIdx.x;
    const int lane = tid & 63;
    const int wid  = tid >> 6;
    const int wr   = wid >> 1;   // 64-row half
    const int wc   = wid & 1;    // 32-col half

    const int tn = blockIdx.x & 15;
    const int tm = blockIdx.x >> 4;
    const int rowBase = tm * BM;
    const int colBase = tn * BN;

    f32x4 acc[3][4][2] = {};

    const char* Xc = (const char*)Xb;
    const char* Wc = (const char*)Wb;

    for (int k0 = 0; k0 < Dn; k0 += BK) {
        // A tile: 128x64 bf16, row stride 128B, dest linear, source inverse-swizzled
        #pragma unroll
        for (int i = 0; i < 4; ++i) {
            int p   = (i * 256 + tid) * 16;
            int row = p >> 7;
            int cb  = p & 127;
            int scb = cb ^ ((row & 7) << 4);
            const void* src = Xc + (size_t)(rowBase + row) * (Dn * 2) + k0 * 2 + scb;
            GLOAD_LDS16(src, (char*)Alds + (i * 256 + wid * 64) * 16);
        }
        // B tiles: 3 x (64x64) bf16
        #pragma unroll
        for (int i = 0; i < 6; ++i) {
            int p   = (i * 256 + tid) * 16;
            int g   = p >> 13;
            int q   = p & 8191;
            int row = q >> 7;
            int cb  = q & 127;
            int scb = cb ^ ((row & 7) << 4);
            const void* src = Wc + (size_t)g * ((size_t)Hn * Dn * 2)
                            + (size_t)(colBase + row) * (Dn * 2) + k0 * 2 + scb;
            GLOAD_LDS16(src, (char*)Blds + (i * 256 + wid * 64) * 16);
        }
        __syncthreads();

        const int l16 = lane & 15;
        const int kql = (lane >> 4) * 16;   // byte offset of this lane's k-octet
        #pragma unroll
        for (int ks = 0; ks < 2; ++ks) {
            const int kb = ks * 64 + kql;
            s16x8 af[4];
            #pragma unroll
            for (int mf = 0; mf < 4; ++mf) {
                int row = wr * 64 + mf * 16 + l16;
                int byt = row * 128 + (kb ^ ((row & 7) << 4));
                af[mf] = *(const s16x8*)((const char*)Alds + byt);
            }
            #pragma unroll
            for (int g = 0; g < 3; ++g) {
                s16x8 bf2[2];
                #pragma unroll
                for (int nf = 0; nf < 2; ++nf) {
                    int row = wc * 32 + nf * 16 + l16;
                    int byt = g * 8192 + row * 128 + (kb ^ ((row & 7) << 4));
                    bf2[nf] = *(const s16x8*)((const char*)Blds + byt);
                }
                #pragma unroll
                for (int mf = 0; mf < 4; ++mf)
                    #pragma unroll
                    for (int nf = 0; nf < 2; ++nf)
                        acc[g][mf][nf] = __builtin_amdgcn_mfma_f32_16x16x32_bf16(
                            af[mf], bf2[nf], acc[g][mf][nf], 0, 0, 0);
            }
        }
        __syncthreads();
    }

    // epilogue: gate math
    const int l16   = lane & 15;
    const int rquad = (lane >> 4) * 4;
    #pragma unroll
    for (int mf = 0; mf < 4; ++mf) {
        #pragma unroll
        for (int nf = 0; nf < 2; ++nf) {
            int col = colBase + wc * 32 + nf * 16 + l16;
            float bfv = bfp[col], biv = bip[col], bhv = bhp[col];
            #pragma unroll
            for (int r = 0; r < 4; ++r) {
                int row = rowBase + wr * 64 + mf * 16 + rquad + r;
                float zf = acc[0][mf][nf][r] + bfv;
                float zi = acc[1][mf][nf][r] + biv;
                float zh = acc[2][mf][nf][r] + bhv;
                float fg = 1.f / (1.f + __expf(-zf));
                float ig = 1.f / (1.f + __expf(-zi));
                float gs = fg + ig + EPSF;
                size_t idx = (size_t)row * Hn + col;
                lr_out[idx] = __logf(fg / gs + EPSF);
                m_out[idx]  = (ig / gs) * zh;
            }
        }
    }
}

// ---------------------------------------------------------------------------
// FALLBACK GEMM (round-1, fused fp32->bf16 staging) — used if ws too small
// ---------------------------------------------------------------------------
__global__ __launch_bounds__(256) void gate_gemm(
    const float* __restrict__ X,
    const float* __restrict__ Wf, const float* __restrict__ bfp,
    const float* __restrict__ Wi, const float* __restrict__ bip,
    const float* __restrict__ Wh, const float* __restrict__ bhp,
    float* __restrict__ lr_out, float* __restrict__ m_out)
{
    constexpr int BM = 128, BN = 64, BK = 32;
    __shared__ unsigned short Alds[BM * BK];
    __shared__ unsigned short Blds[3][BN * BK];

    const int tid  = threadIdx.x;
    const int lane = tid & 63;
    const int wid  = tid >> 6;
    const int wr   = wid >> 1;
    const int wc   = wid & 1;

    const int tn = blockIdx.x & 15;
    const int tm = blockIdx.x >> 4;
    const int rowBase = tm * BM;
    const int colBase = tn * BN;

    f32x4 acc[3][4][2] = {};
    const float* Wg[3] = {Wf, Wi, Wh};

    for (int k0 = 0; k0 < Dn; k0 += BK) {
        #pragma unroll
        for (int i = 0; i < 4; ++i) {
            int li = tid + 256 * i;
            int r  = li >> 3;
            int c  = (li & 7) << 2;
            const float4 v = *(const float4*)(X + (size_t)(rowBase + r) * Dn + k0 + c);
            ushort4 hv;
            hv.x = f2bf(v.x); hv.y = f2bf(v.y); hv.z = f2bf(v.z); hv.w = f2bf(v.w);
            *(ushort4*)(&Alds[r * BK + c]) = hv;
        }
        #pragma unroll
        for (int g = 0; g < 3; ++g) {
            #pragma unroll
            for (int i = 0; i < 2; ++i) {
                int li = tid + 256 * i;
                int r  = li >> 3;
                int c  = (li & 7) << 2;
                const float4 v = *(const float4*)(Wg[g] + (size_t)(colBase + r) * Dn + k0 + c);
                ushort4 hv;
                hv.x = f2bf(v.x); hv.y = f2bf(v.y); hv.z = f2bf(v.z); hv.w = f2bf(v.w);
                *(ushort4*)(&Blds[g][r * BK + c]) = hv;
            }
        }
        __syncthreads();

        const int kq  = (lane >> 4) << 3;
        const int l16 = lane & 15;
        s16x8 af[4];
        #pragma unroll
        for (int mf = 0; mf < 4; ++mf) {
            int row = wr * 64 + mf * 16 + l16;
            af[mf] = *(const s16x8*)(&Alds[row * BK + kq]);
        }
        #pragma unroll
        for (int g = 0; g < 3; ++g) {
            s16x8 bfr[2];
            #pragma unroll
            for (int nf = 0; nf < 2; ++nf) {
                int col = wc * 32 + nf * 16 + l16;
                bfr[nf] = *(const s16x8*)(&Blds[g][col * BK + kq]);
            }
            #pragma unroll
            for (int mf = 0; mf < 4; ++mf)
                #pragma unroll
                for (int nf = 0; nf < 2; ++nf)
                    acc[g][mf][nf] = __builtin_amdgcn_mfma_f32_16x16x32_bf16(
                        af[mf], bfr[nf], acc[g][mf][nf], 0, 0, 0);
        }
        __syncthreads();
    }

    const int l16   = lane & 15;
    const int rquad = (lane >> 4) * 4;
    #pragma unroll
    for (int mf = 0; mf < 4; ++mf) {
        #pragma unroll
        for (int nf = 0; nf < 2; ++nf) {
            int col = colBase + wc * 32 + nf * 16 + l16;
            float bfv = bfp[col], biv = bip[col], bhv = bhp[col];
            #pragma unroll
            for (int r = 0; r < 4; ++r) {
                int row = rowBase + wr * 64 + mf * 16 + rquad + r;
                float zf = acc[0][mf][nf][r] + bfv;
                float zi = acc[1][mf][nf][r] + biv;
                float zh = acc[2][mf][nf][r] + bhv;
                float fg = 1.f / (1.f + __expf(-zf));
                float ig = 1.f / (1.f + __expf(-zi));
                float gs = fg + ig + EPSF;
                size_t idx = (size_t)row * Hn + col;
                lr_out[idx] = __logf(fg / gs + EPSF);
                m_out[idx]  = (ig / gs) * zh;
            }
        }
    }
}

// ---------------------------------------------------------------------------
// Chunked scan, pass 1: per (b,h,chunk): lc = sum(lr), cc = sum(exp(suffix)*m)
// suffix anchored at chunk end -> exponent always <= 0, no overflow.
// ---------------------------------------------------------------------------
__global__ __launch_bounds__(256) void scan_chunks(
    const float* __restrict__ lr, const float* __restrict__ m,
    float* __restrict__ lcA, float* __restrict__ ccA)
{
    int g  = blockIdx.x * 256 + threadIdx.x;   // 0..131071
    int h  = g & 1023;
    int bc = g >> 10;
    int b  = bc & 7;
    int c  = bc >> 3;
    const size_t base = ((size_t)b * Sn + (size_t)c * CH) * Hn + h;

    float s = 0.f, cc = 0.f;
    #pragma unroll 4
    for (int t = CH - 1; t >= 0; --t) {
        s += lr[base + (size_t)t * Hn];
        cc += __expf(s) * m[base + (size_t)t * Hn];
    }
    int o = c * (Bn * Hn) + b * Hn + h;
    lcA[o] = s;
    ccA[o] = cc;
}

// ---------------------------------------------------------------------------
// Chunked scan, pass 2: combine chunk prefixes (log space), replay chunk.
// hidden_t = accPref + sum_{u in chunk, u<=t} exp(Ltot - L_{u-1})*m_u + exp(L_t)*h0
// ---------------------------------------------------------------------------
__global__ __launch_bounds__(256) void scan_apply(
    const float* __restrict__ lr, float* __restrict__ io,
    const float* __restrict__ h0,
    const float* __restrict__ lcA, const float* __restrict__ ccA)
{
    int g  = blockIdx.x * 256 + threadIdx.x;
    int h  = g & 1023;
    int bc = g >> 10;
    int b  = bc & 7;
    int c  = bc >> 3;
    const int bh = b * Hn + h;

    float lcv[NC], ccv[NC], pref[NC];
    #pragma unroll
    for (int j = 0; j < NC; ++j) {
        lcv[j] = lcA[j * (Bn * Hn) + bh];
        ccv[j] = ccA[j * (Bn * Hn) + bh];
    }
    float run = 0.f;
    #pragma unroll
    for (int j = 0; j < NC; ++j) { run += lcv[j]; pref[j] = run; }
    const float Ltot = run;

    float Lpre = 0.f, acc = 0.f;
    #pragma unroll
    for (int j = 0; j < NC; ++j) {
        if (j < c) {
            Lpre += lcv[j];
            acc  += __expf(Ltot - pref[j]) * ccv[j];
        }
    }

    const float h0v = h0[bh];
    const size_t base = ((size_t)b * Sn + (size_t)c * CH) * Hn + h;
    float L = Lpre;
    #pragma unroll 4
    for (int t = 0; t < CH; ++t) {
        float mv = io[base + (size_t)t * Hn];
        float lv = lr[base + (size_t)t * Hn];
        acc += __expf(Ltot - L) * mv;   // L = L_{t-1}
        L += lv;
        io[base + (size_t)t * Hn] = acc + __expf(L) * h0v;
    }
}

// ---------------------------------------------------------------------------
// FALLBACK scan (round-1, 1 thread per (b,h))
// ---------------------------------------------------------------------------
__global__ __launch_bounds__(64) void scan_kernel(
    const float* __restrict__ lr, float* __restrict__ io,
    const float* __restrict__ h0)
{
    const int tid = blockIdx.x * 64 + threadIdx.x;
    const int b  = tid >> 10;
    const int hh = tid & 1023;
    const float* lrp = lr + (size_t)b * Sn * Hn + hh;
    float*       iop = io + (size_t)b * Sn * Hn + hh;

    float Lt = 0.f;
    #pragma unroll 8
    for (int t = 0; t < Sn; ++t) Lt += lrp[(size_t)t * Hn];

    float L = 0.f, acc = 0.f;
    const float h0v = h0[tid];
    #pragma unroll 4
    for (int t = 0; t < Sn; ++t) {
        float mv = iop[(size_t)t * Hn];
        float lv = lrp[(size_t)t * Hn];
        acc += __expf(Lt - L) * mv;
        L += lv;
        iop[(size_t)t * Hn] = acc + __expf(L) * h0v;
    }
}

extern "C" void kernel_launch(void* const* d_in, const int* in_sizes, int n_in,
                              void* d_out, int out_size, void* d_ws, size_t ws_size,
                              hipStream_t stream)
{
    const float* X  = (const float*)d_in[0];
    const float* h0 = (const float*)d_in[1];
    const float* Wf = (const float*)d_in[2];
    const float* bf = (const float*)d_in[3];
    const float* Wi = (const float*)d_in[4];
    const float* bi = (const float*)d_in[5];
    const float* Wh = (const float*)d_in[6];
    const float* bh = (const float*)d_in[7];
    float* out = (float*)d_out;

    char*  base = (char*)d_ws;
    float* lr   = (float*)d_ws;                       // 64 MB
    const size_t szLR = (size_t)Mn * Hn * 4;          // 64 MB
    const size_t szX  = (size_t)Mn * Dn * 2;          // 32 MB
    const size_t szW  = (size_t)3 * Hn * Dn * 2;      // 6 MB
    const size_t szC  = (size_t)2 * NC * Bn * Hn * 4; // 1 MB

    const bool fastgemm = ws_size >= szLR + szX + szW + szC;
    const bool fastscan = fastgemm || (ws_size >= szLR + szC);

    const int grid = (Mn / 128) * (Hn / 64);   // 2048 blocks

    if (fastgemm) {
        unsigned short* Xb = (unsigned short*)(base + szLR);
        unsigned short* Wb = (unsigned short*)(base + szLR + szX);
        cvt_bf16<<<(Mn * Dn / 8) / 256, 256, 0, stream>>>(X, Xb, Mn * Dn / 8);
        cvt_bf16<<<(Hn * Dn / 8 + 255) / 256, 256, 0, stream>>>(Wf, Wb, Hn * Dn / 8);
        cvt_bf16<<<(Hn * Dn / 8 + 255) / 256, 256, 0, stream>>>(Wi, Wb + (size_t)Hn * Dn, Hn * Dn / 8);
        cvt_bf16<<<(Hn * Dn / 8 + 255) / 256, 256, 0, stream>>>(Wh, Wb + (size_t)2 * Hn * Dn, Hn * Dn / 8);
        gate_gemm_bf<<<grid, 256, 0, stream>>>(Xb, Wb, bf, bi, bh, lr, out);
    } else {
        gate_gemm<<<grid, 256, 0, stream>>>(X, Wf, bf, Wi, bi, Wh, bh, lr, out);
    }

    if (fastscan) {
        float* chunkBase = (float*)(base + (fastgemm ? szLR + szX + szW : szLR));
        float* lcA = chunkBase;
        float* ccA = chunkBase + (size_t)NC * Bn * Hn;
        scan_chunks<<<(Bn * Hn * NC) / 256, 256, 0, stream>>>(lr, out, lcA, ccA);
        scan_apply<<<(Bn * Hn * NC) / 256, 256, 0, stream>>>(lr, out, h0, lcA, ccA);
    } else {
        scan_kernel<<<(Bn * Hn) / 64, 64, 0, stream>>>(lr, out, h0);
    }
}

// Round 3
// 197.727 us; speedup vs baseline: 2.6373x; 1.0329x over previous
//
#include <hip/hip_runtime.h>
#include <hip/hip_bf16.h>

#define EPSF 1e-8f

// Problem sizes (fixed by reference setup_inputs)
constexpr int Bn = 8, Sn = 2048, Dn = 1024, Hn = 1024;
constexpr int Mn = Bn * Sn;          // 16384 rows of X
constexpr int CH = 128;              // scan chunk length
constexpr int NC = Sn / CH;          // 16 chunks

typedef short s16x8 __attribute__((ext_vector_type(8)));
typedef float f32x4 __attribute__((ext_vector_type(4)));

__device__ __forceinline__ unsigned short f2bf(float x) {
    unsigned u = __float_as_uint(x);
    u += 0x7FFFu + ((u >> 16) & 1u);
    return (unsigned short)(u >> 16);
}

#define GLOAD_LDS16(gaddr, laddr)                                              \
    __builtin_amdgcn_global_load_lds(                                          \
        (const __attribute__((address_space(1))) void*)(gaddr),                \
        (__attribute__((address_space(3))) void*)(laddr), 16, 0, 0)

// ---------------------------------------------------------------------------
// fp32 -> bf16 converts
// ---------------------------------------------------------------------------
__global__ __launch_bounds__(256) void cvt_bf16(const float* __restrict__ src,
                                                unsigned short* __restrict__ dst,
                                                int n8)
{
    int g = blockIdx.x * 256 + threadIdx.x;
    if (g >= n8) return;
    const float4* s4 = (const float4*)src;
    float4 a = s4[g * 2], b = s4[g * 2 + 1];
    ushort4 lo, hi;
    lo.x = f2bf(a.x); lo.y = f2bf(a.y); lo.z = f2bf(a.z); lo.w = f2bf(a.w);
    hi.x = f2bf(b.x); hi.y = f2bf(b.y); hi.z = f2bf(b.z); hi.w = f2bf(b.w);
    ((ushort4*)dst)[g * 2]     = lo;
    ((ushort4*)dst)[g * 2 + 1] = hi;
}

// all three weight matrices in one launch: dst layout [3][Hn*Dn]
__global__ __launch_bounds__(256) void cvt_w3(const float* __restrict__ w0,
                                              const float* __restrict__ w1,
                                              const float* __restrict__ w2,
                                              unsigned short* __restrict__ dst)
{
    int g = blockIdx.x * 256 + threadIdx.x;        // 0 .. 3*131072-1
    int m = g >> 17;
    int r = g & 131071;
    const float* src = (m == 0) ? w0 : ((m == 1) ? w1 : w2);
    const float4* s4 = (const float4*)src;
    float4 a = s4[r * 2], b = s4[r * 2 + 1];
    ushort4 lo, hi;
    lo.x = f2bf(a.x); lo.y = f2bf(a.y); lo.z = f2bf(a.z); lo.w = f2bf(a.w);
    hi.x = f2bf(b.x); hi.y = f2bf(b.y); hi.z = f2bf(b.z); hi.w = f2bf(b.w);
    ushort4* d4 = (ushort4*)(dst + ((size_t)m << 20));
    d4[r * 2]     = lo;
    d4[r * 2 + 1] = hi;
}

// ---------------------------------------------------------------------------
// FAST GEMM: bf16 in, global_load_lds staging, XOR-swizzled LDS,
// double-buffered 2-phase prefetch, hoisted addressing.
// ---------------------------------------------------------------------------
__global__ __launch_bounds__(256) void gate_gemm_bf(
    const unsigned short* __restrict__ Xb,
    const unsigned short* __restrict__ Wb,   // [3][Hn][Dn] bf16 concat
    const float* __restrict__ bfp, const float* __restrict__ bip,
    const float* __restrict__ bhp,
    float* __restrict__ lr_out, float* __restrict__ m_out)
{
    constexpr int BM = 128, BN = 64;
    constexpr int BUF = 40960;                 // 16KB A + 24KB B per buffer
    __shared__ __align__(16) char lds[2 * BUF];

    const int tid  = threadIdx.x;
    const int lane = tid & 63;
    const int wid  = tid >> 6;
    const int wr   = wid >> 1;   // 64-row half
    const int wc   = wid & 1;    // 32-col half

    // XCD-chunked bijective swizzle (2048 % 8 == 0): each XCD gets 256
    // contiguous logical tiles -> 16 tm-groups sharing a 4MB A slice.
    const int bid = blockIdx.x;
    const int wg  = (bid & 7) * 256 + (bid >> 3);
    const int tn = wg & 15;
    const int tm = wg >> 4;
    const int rowBase = tm * BM;
    const int colBase = tn * BN;

    f32x4 acc[3][4][2] = {};

    // ---- staging bases (loop-invariant): row&7 == (tid>>3)&7 for every load
    const int rA   = tid >> 3;                  // 0..31
    const int cbyt = (tid & 7) * 16;            // 0..112
    const int scb  = cbyt ^ ((rA & 7) << 4);    // swizzled source byte col
    const char* pA = (const char*)Xb + (size_t)(rowBase + rA) * (Dn * 2) + scb;
    const char* pB = (const char*)Wb + (size_t)(colBase + rA) * (Dn * 2) + scb;
    const int dstA = wid * 1024;                // + i*4096
    const int dstB = 16384 + wid * 1024;        // + i*4096

    // ---- ds_read byte offsets (loop-invariant)
    const int l16 = lane & 15;
    const int kql = (lane >> 4) * 16;
    int aOff[2][4], bOff[2][6];
    #pragma unroll
    for (int ks = 0; ks < 2; ++ks) {
        const int kb = ks * 64 + kql;
        #pragma unroll
        for (int mf = 0; mf < 4; ++mf) {
            int row = wr * 64 + mf * 16 + l16;
            aOff[ks][mf] = row * 128 + (kb ^ ((row & 7) << 4));
        }
        #pragma unroll
        for (int g = 0; g < 3; ++g)
            #pragma unroll
            for (int nf = 0; nf < 2; ++nf) {
                int row = wc * 32 + nf * 16 + l16;
                bOff[ks][g * 2 + nf] = 16384 + g * 8192 + row * 128 + (kb ^ ((row & 7) << 4));
            }
    }

    auto stage = [&](char* ldsbase, int k0) {
        const char* pa = pA + k0 * 2;
        #pragma unroll
        for (int i = 0; i < 4; ++i)
            GLOAD_LDS16(pa + i * 65536, ldsbase + dstA + i * 4096);
        const char* pb = pB + k0 * 2;
        #pragma unroll
        for (int i = 0; i < 6; ++i)
            GLOAD_LDS16(pb + (i >> 1) * 2097152 + (i & 1) * 65536,
                        ldsbase + dstB + i * 4096);
    };

    auto compute = [&](const char* base) {
        #pragma unroll
        for (int ks = 0; ks < 2; ++ks) {
            s16x8 af[4];
            #pragma unroll
            for (int mf = 0; mf < 4; ++mf)
                af[mf] = *(const s16x8*)(base + aOff[ks][mf]);
            #pragma unroll
            for (int g = 0; g < 3; ++g) {
                s16x8 bf2[2];
                #pragma unroll
                for (int nf = 0; nf < 2; ++nf)
                    bf2[nf] = *(const s16x8*)(base + bOff[ks][g * 2 + nf]);
                #pragma unroll
                for (int mf = 0; mf < 4; ++mf)
                    #pragma unroll
                    for (int nf = 0; nf < 2; ++nf)
                        acc[g][mf][nf] = __builtin_amdgcn_mfma_f32_16x16x32_bf16(
                            af[mf], bf2[nf], acc[g][mf][nf], 0, 0, 0);
            }
        }
    };

    // ---- prologue
    int cur = 0;
    stage(lds, 0);
    asm volatile("s_waitcnt vmcnt(0)" ::: "memory");
    __syncthreads();

    // ---- main loop: prefetch next tile, compute current
    for (int k0 = 64; k0 < Dn; k0 += 64) {
        stage(lds + (cur ^ 1) * BUF, k0);
        compute(lds + cur * BUF);
        asm volatile("s_waitcnt vmcnt(0)" ::: "memory");
        __syncthreads();
        cur ^= 1;
    }
    compute(lds + cur * BUF);

    // ---- epilogue: gate math
    const int rquad = (lane >> 4) * 4;
    #pragma unroll
    for (int mf = 0; mf < 4; ++mf) {
        #pragma unroll
        for (int nf = 0; nf < 2; ++nf) {
            int col = colBase + wc * 32 + nf * 16 + l16;
            float bfv = bfp[col], biv = bip[col], bhv = bhp[col];
            #pragma unroll
            for (int r = 0; r < 4; ++r) {
                int row = rowBase + wr * 64 + mf * 16 + rquad + r;
                float zf = acc[0][mf][nf][r] + bfv;
                float zi = acc[1][mf][nf][r] + biv;
                float zh = acc[2][mf][nf][r] + bhv;
                float fg = 1.f / (1.f + __expf(-zf));
                float ig = 1.f / (1.f + __expf(-zi));
                float gs = fg + ig + EPSF;
                size_t idx = (size_t)row * Hn + col;
                lr_out[idx] = __logf(fg / gs + EPSF);
                m_out[idx]  = (ig / gs) * zh;
            }
        }
    }
}

// ---------------------------------------------------------------------------
// FALLBACK GEMM (fused fp32->bf16 staging) — used if ws too small
// ---------------------------------------------------------------------------
__global__ __launch_bounds__(256) void gate_gemm(
    const float* __restrict__ X,
    const float* __restrict__ Wf, const float* __restrict__ bfp,
    const float* __restrict__ Wi, const float* __restrict__ bip,
    const float* __restrict__ Wh, const float* __restrict__ bhp,
    float* __restrict__ lr_out, float* __restrict__ m_out)
{
    constexpr int BM = 128, BN = 64, BK = 32;
    __shared__ unsigned short Alds[BM * BK];
    __shared__ unsigned short Blds[3][BN * BK];

    const int tid  = threadIdx.x;
    const int lane = tid & 63;
    const int wid  = tid >> 6;
    const int wr   = wid >> 1;
    const int wc   = wid & 1;

    const int tn = blockIdx.x & 15;
    const int tm = blockIdx.x >> 4;
    const int rowBase = tm * BM;
    const int colBase = tn * BN;

    f32x4 acc[3][4][2] = {};
    const float* Wg[3] = {Wf, Wi, Wh};

    for (int k0 = 0; k0 < Dn; k0 += BK) {
        #pragma unroll
        for (int i = 0; i < 4; ++i) {
            int li = tid + 256 * i;
            int r  = li >> 3;
            int c  = (li & 7) << 2;
            const float4 v = *(const float4*)(X + (size_t)(rowBase + r) * Dn + k0 + c);
            ushort4 hv;
            hv.x = f2bf(v.x); hv.y = f2bf(v.y); hv.z = f2bf(v.z); hv.w = f2bf(v.w);
            *(ushort4*)(&Alds[r * BK + c]) = hv;
        }
        #pragma unroll
        for (int g = 0; g < 3; ++g) {
            #pragma unroll
            for (int i = 0; i < 2; ++i) {
                int li = tid + 256 * i;
                int r  = li >> 3;
                int c  = (li & 7) << 2;
                const float4 v = *(const float4*)(Wg[g] + (size_t)(colBase + r) * Dn + k0 + c);
                ushort4 hv;
                hv.x = f2bf(v.x); hv.y = f2bf(v.y); hv.z = f2bf(v.z); hv.w = f2bf(v.w);
                *(ushort4*)(&Blds[g][r * BK + c]) = hv;
            }
        }
        __syncthreads();

        const int kq  = (lane >> 4) << 3;
        const int l16 = lane & 15;
        s16x8 af[4];
        #pragma unroll
        for (int mf = 0; mf < 4; ++mf) {
            int row = wr * 64 + mf * 16 + l16;
            af[mf] = *(const s16x8*)(&Alds[row * BK + kq]);
        }
        #pragma unroll
        for (int g = 0; g < 3; ++g) {
            s16x8 bfr[2];
            #pragma unroll
            for (int nf = 0; nf < 2; ++nf) {
                int col = wc * 32 + nf * 16 + l16;
                bfr[nf] = *(const s16x8*)(&Blds[g][col * BK + kq]);
            }
            #pragma unroll
            for (int mf = 0; mf < 4; ++mf)
                #pragma unroll
                for (int nf = 0; nf < 2; ++nf)
                    acc[g][mf][nf] = __builtin_amdgcn_mfma_f32_16x16x32_bf16(
                        af[mf], bfr[nf], acc[g][mf][nf], 0, 0, 0);
        }
        __syncthreads();
    }

    const int l16   = lane & 15;
    const int rquad = (lane >> 4) * 4;
    #pragma unroll
    for (int mf = 0; mf < 4; ++mf) {
        #pragma unroll
        for (int nf = 0; nf < 2; ++nf) {
            int col = colBase + wc * 32 + nf * 16 + l16;
            float bfv = bfp[col], biv = bip[col], bhv = bhp[col];
            #pragma unroll
            for (int r = 0; r < 4; ++r) {
                int row = rowBase + wr * 64 + mf * 16 + rquad + r;
                float zf = acc[0][mf][nf][r] + bfv;
                float zi = acc[1][mf][nf][r] + biv;
                float zh = acc[2][mf][nf][r] + bhv;
                float fg = 1.f / (1.f + __expf(-zf));
                float ig = 1.f / (1.f + __expf(-zi));
                float gs = fg + ig + EPSF;
                size_t idx = (size_t)row * Hn + col;
                lr_out[idx] = __logf(fg / gs + EPSF);
                m_out[idx]  = (ig / gs) * zh;
            }
        }
    }
}

// ---------------------------------------------------------------------------
// Chunked scan, pass 1
// ---------------------------------------------------------------------------
__global__ __launch_bounds__(256) void scan_chunks(
    const float* __restrict__ lr, const float* __restrict__ m,
    float* __restrict__ lcA, float* __restrict__ ccA)
{
    int g  = blockIdx.x * 256 + threadIdx.x;
    int h  = g & 1023;
    int bc = g >> 10;
    int b  = bc & 7;
    int c  = bc >> 3;
    const size_t base = ((size_t)b * Sn + (size_t)c * CH) * Hn + h;

    float s = 0.f, cc = 0.f;
    #pragma unroll 4
    for (int t = CH - 1; t >= 0; --t) {
        s += lr[base + (size_t)t * Hn];
        cc += __expf(s) * m[base + (size_t)t * Hn];
    }
    int o = c * (Bn * Hn) + b * Hn + h;
    lcA[o] = s;
    ccA[o] = cc;
}

// ---------------------------------------------------------------------------
// Chunked scan, pass 2
// ---------------------------------------------------------------------------
__global__ __launch_bounds__(256) void scan_apply(
    const float* __restrict__ lr, float* __restrict__ io,
    const float* __restrict__ h0,
    const float* __restrict__ lcA, const float* __restrict__ ccA)
{
    int g  = blockIdx.x * 256 + threadIdx.x;
    int h  = g & 1023;
    int bc = g >> 10;
    int b  = bc & 7;
    int c  = bc >> 3;
    const int bh = b * Hn + h;

    float lcv[NC], ccv[NC], pref[NC];
    #pragma unroll
    for (int j = 0; j < NC; ++j) {
        lcv[j] = lcA[j * (Bn * Hn) + bh];
        ccv[j] = ccA[j * (Bn * Hn) + bh];
    }
    float run = 0.f;
    #pragma unroll
    for (int j = 0; j < NC; ++j) { run += lcv[j]; pref[j] = run; }
    const float Ltot = run;

    float Lpre = 0.f, acc = 0.f;
    #pragma unroll
    for (int j = 0; j < NC; ++j) {
        if (j < c) {
            Lpre += lcv[j];
            acc  += __expf(Ltot - pref[j]) * ccv[j];
        }
    }

    const float h0v = h0[bh];
    const size_t base = ((size_t)b * Sn + (size_t)c * CH) * Hn + h;
    float L = Lpre;
    #pragma unroll 4
    for (int t = 0; t < CH; ++t) {
        float mv = io[base + (size_t)t * Hn];
        float lv = lr[base + (size_t)t * Hn];
        acc += __expf(Ltot - L) * mv;   // L = L_{t-1}
        L += lv;
        io[base + (size_t)t * Hn] = acc + __expf(L) * h0v;
    }
}

// ---------------------------------------------------------------------------
// FALLBACK scan
// ---------------------------------------------------------------------------
__global__ __launch_bounds__(64) void scan_kernel(
    const float* __restrict__ lr, float* __restrict__ io,
    const float* __restrict__ h0)
{
    const int tid = blockIdx.x * 64 + threadIdx.x;
    const int b  = tid >> 10;
    const int hh = tid & 1023;
    const float* lrp = lr + (size_t)b * Sn * Hn + hh;
    float*       iop = io + (size_t)b * Sn * Hn + hh;

    float Lt = 0.f;
    #pragma unroll 8
    for (int t = 0; t < Sn; ++t) Lt += lrp[(size_t)t * Hn];

    float L = 0.f, acc = 0.f;
    const float h0v = h0[tid];
    #pragma unroll 4
    for (int t = 0; t < Sn; ++t) {
        float mv = iop[(size_t)t * Hn];
        float lv = lrp[(size_t)t * Hn];
        acc += __expf(Lt - L) * mv;
        L += lv;
        iop[(size_t)t * Hn] = acc + __expf(L) * h0v;
    }
}

extern "C" void kernel_launch(void* const* d_in, const int* in_sizes, int n_in,
                              void* d_out, int out_size, void* d_ws, size_t ws_size,
                              hipStream_t stream)
{
    const float* X  = (const float*)d_in[0];
    const float* h0 = (const float*)d_in[1];
    const float* Wf = (const float*)d_in[2];
    const float* bf = (const float*)d_in[3];
    const float* Wi = (const float*)d_in[4];
    const float* bi = (const float*)d_in[5];
    const float* Wh = (const float*)d_in[6];
    const float* bh = (const float*)d_in[7];
    float* out = (float*)d_out;

    char*  base = (char*)d_ws;
    float* lr   = (float*)d_ws;                       // 64 MB
    const size_t szLR = (size_t)Mn * Hn * 4;          // 64 MB
    const size_t szX  = (size_t)Mn * Dn * 2;          // 32 MB
    const size_t szW  = (size_t)3 * Hn * Dn * 2;      // 6 MB
    const size_t szC  = (size_t)2 * NC * Bn * Hn * 4; // 1 MB

    const bool fastgemm = ws_size >= szLR + szX + szW + szC;
    const bool fastscan = fastgemm || (ws_size >= szLR + szC);

    const int grid = (Mn / 128) * (Hn / 64);   // 2048 blocks

    if (fastgemm) {
        unsigned short* Xb = (unsigned short*)(base + szLR);
        unsigned short* Wb = (unsigned short*)(base + szLR + szX);
        cvt_bf16<<<(Mn * Dn / 8) / 256, 256, 0, stream>>>(X, Xb, Mn * Dn / 8);
        cvt_w3<<<(3 * Hn * Dn / 8) / 256, 256, 0, stream>>>(Wf, Wi, Wh, Wb);
        gate_gemm_bf<<<grid, 256, 0, stream>>>(Xb, Wb, bf, bi, bh, lr, out);
    } else {
        gate_gemm<<<grid, 256, 0, stream>>>(X, Wf, bf, Wi, bi, Wh, bh, lr, out);
    }

    if (fastscan) {
        float* chunkBase = (float*)(base + (fastgemm ? szLR + szX + szW : szLR));
        float* lcA = chunkBase;
        float* ccA = chunkBase + (size_t)NC * Bn * Hn;
        scan_chunks<<<(Bn * Hn * NC) / 256, 256, 0, stream>>>(lr, out, lcA, ccA);
        scan_apply<<<(Bn * Hn * NC) / 256, 256, 0, stream>>>(lr, out, h0, lcA, ccA);
    } else {
        scan_kernel<<<(Bn * Hn) / 64, 64, 0, stream>>>(lr, out, h0);
    }
}

// Round 4
// 191.503 us; speedup vs baseline: 2.7231x; 1.0325x over previous
//
#include <hip/hip_runtime.h>
#include <hip/hip_bf16.h>

#define EPSF 1e-8f

// Problem sizes (fixed by reference setup_inputs)
constexpr int Bn = 8, Sn = 2048, Dn = 1024, Hn = 1024;
constexpr int Mn = Bn * Sn;          // 16384 rows of X
constexpr int CH = 128;              // scan chunk length
constexpr int NC = Sn / CH;          // 16 chunks

typedef short s16x8 __attribute__((ext_vector_type(8)));
typedef float f32x4 __attribute__((ext_vector_type(4)));

__device__ __forceinline__ unsigned short f2bf(float x) {
    unsigned u = __float_as_uint(x);
    u += 0x7FFFu + ((u >> 16) & 1u);
    return (unsigned short)(u >> 16);
}

#define GLOAD_LDS16(gaddr, laddr)                                              \
    __builtin_amdgcn_global_load_lds(                                          \
        (const __attribute__((address_space(1))) void*)(gaddr),                \
        (__attribute__((address_space(3))) void*)(laddr), 16, 0, 0)

// ---------------------------------------------------------------------------
// fp32 -> bf16 converts
// ---------------------------------------------------------------------------
__global__ __launch_bounds__(256) void cvt_bf16(const float* __restrict__ src,
                                                unsigned short* __restrict__ dst,
                                                int n8)
{
    int g = blockIdx.x * 256 + threadIdx.x;
    if (g >= n8) return;
    const float4* s4 = (const float4*)src;
    float4 a = s4[g * 2], b = s4[g * 2 + 1];
    ushort4 lo, hi;
    lo.x = f2bf(a.x); lo.y = f2bf(a.y); lo.z = f2bf(a.z); lo.w = f2bf(a.w);
    hi.x = f2bf(b.x); hi.y = f2bf(b.y); hi.z = f2bf(b.z); hi.w = f2bf(b.w);
    ((ushort4*)dst)[g * 2]     = lo;
    ((ushort4*)dst)[g * 2 + 1] = hi;
}

// all three weight matrices in one launch: dst layout [3][Hn*Dn]
__global__ __launch_bounds__(256) void cvt_w3(const float* __restrict__ w0,
                                              const float* __restrict__ w1,
                                              const float* __restrict__ w2,
                                              unsigned short* __restrict__ dst)
{
    int g = blockIdx.x * 256 + threadIdx.x;        // 0 .. 3*131072-1
    int m = g >> 17;
    int r = g & 131071;
    const float* src = (m == 0) ? w0 : ((m == 1) ? w1 : w2);
    const float4* s4 = (const float4*)src;
    float4 a = s4[r * 2], b = s4[r * 2 + 1];
    ushort4 lo, hi;
    lo.x = f2bf(a.x); lo.y = f2bf(a.y); lo.z = f2bf(a.z); lo.w = f2bf(a.w);
    hi.x = f2bf(b.x); hi.y = f2bf(b.y); hi.z = f2bf(b.z); hi.w = f2bf(b.w);
    ushort4* d4 = (ushort4*)(dst + ((size_t)m << 20));
    d4[r * 2]     = lo;
    d4[r * 2 + 1] = hi;
}

// ---------------------------------------------------------------------------
// FAST GEMM: 8-phase-style schedule (T3+T4+T5), bf16 in, global_load_lds
// staging, XOR-swizzled LDS, 256x64 tile, 8 waves, dbuf with counted drain.
// ---------------------------------------------------------------------------
__global__ __launch_bounds__(512, 2) void gate_gemm_bf(
    const unsigned short* __restrict__ Xb,
    const unsigned short* __restrict__ Wb,   // [3][Hn][Dn] bf16 concat
    const float* __restrict__ bfp, const float* __restrict__ bip,
    const float* __restrict__ bhp,
    float* __restrict__ lr_out, float* __restrict__ m_out)
{
    constexpr int BUFSZ = 57344;               // 32KB A + 24KB B
    __shared__ __align__(16) char lds[2 * BUFSZ];   // 112 KB

    const int tid  = threadIdx.x;
    const int lane = tid & 63;
    const int wid  = tid >> 6;       // 0..7
    const int wr   = wid >> 1;       // 0..3  (64-row strip)
    const int wc   = wid & 1;        // 0..1  (32-col strip)

    // XCD-chunked bijective mapping: 8 consecutive blocks per XCD share one
    // tn (B chunk, 384KB) while walking an XCD-private 4MB A slice.
    const int bid = blockIdx.x;
    const int xcd = bid & 7;
    const int idx = bid >> 3;              // 0..127
    const int tn  = idx >> 3;              // 0..15
    const int tm  = (idx & 7) + xcd * 8;   // 0..63
    const int rowBase = tm * 256;
    const int colBase = tn * 64;

    f32x4 acc[3][4][2] = {};

    // ---- staging addressing (loop-invariant)
    const int rstg = tid >> 3;                         // 0..63
    const int scb  = ((tid & 7) * 16) ^ ((rstg & 7) << 4);
    const char* pA = (const char*)Xb + (size_t)(rowBase + rstg) * 2048 + scb;
    const char* pB = (const char*)Wb + (size_t)(colBase + rstg) * 2048 + scb;
    const int dstOff = tid * 16;

    // ---- ds_read byte offsets (loop-invariant)
    const int l16 = lane & 15;
    const int kql = (lane >> 4) * 16;
    int aOff[2][4], bOff[2][6];
    #pragma unroll
    for (int ks = 0; ks < 2; ++ks) {
        const int kb = ks * 64 + kql;
        #pragma unroll
        for (int mf = 0; mf < 4; ++mf) {
            int row = wr * 64 + mf * 16 + l16;
            aOff[ks][mf] = row * 128 + (kb ^ ((l16 & 7) << 4));
        }
        #pragma unroll
        for (int g = 0; g < 3; ++g)
            #pragma unroll
            for (int nf = 0; nf < 2; ++nf) {
                int row = wc * 32 + nf * 16 + l16;
                bOff[ks][g * 2 + nf] = 32768 + g * 8192 + row * 128
                                     + (kb ^ ((l16 & 7) << 4));
            }
    }

    auto stageA = [&](char* buf, int k0) {
        #pragma unroll
        for (int i = 0; i < 4; ++i)
            GLOAD_LDS16(pA + (size_t)i * 131072 + k0 * 2, buf + i * 8192 + dstOff);
    };
    auto stageB = [&](char* buf, int k0) {
        #pragma unroll
        for (int j = 0; j < 3; ++j)
            GLOAD_LDS16(pB + (size_t)j * 2097152 + k0 * 2,
                        buf + 32768 + j * 8192 + dstOff);
    };

    // One phase: [stage half of next tile] || ds_read frags -> barrier ->
    // lgkmcnt(0) -> MFMA cluster (setprio) -> [drain] -> barrier
    auto phase = [&](const char* cur, int ks, bool stA, bool stB,
                     char* nxt, int k0n, bool drain) {
        if (stA) stageA(nxt, k0n);
        if (stB) stageB(nxt, k0n);
        s16x8 af[4], bf2[6];
        #pragma unroll
        for (int mf = 0; mf < 4; ++mf)
            af[mf] = *(const s16x8*)(cur + aOff[ks][mf]);
        #pragma unroll
        for (int j = 0; j < 6; ++j)
            bf2[j] = *(const s16x8*)(cur + bOff[ks][j]);
        __builtin_amdgcn_s_barrier();
        asm volatile("s_waitcnt lgkmcnt(0)" ::: "memory");
        __builtin_amdgcn_sched_barrier(0);
        __builtin_amdgcn_s_setprio(1);
        #pragma unroll
        for (int g = 0; g < 3; ++g)
            #pragma unroll
            for (int mf = 0; mf < 4; ++mf)
                #pragma unroll
                for (int nf = 0; nf < 2; ++nf)
                    acc[g][mf][nf] = __builtin_amdgcn_mfma_f32_16x16x32_bf16(
                        af[mf], bf2[g * 2 + nf], acc[g][mf][nf], 0, 0, 0);
        __builtin_amdgcn_s_setprio(0);
        if (drain)
            asm volatile("s_waitcnt vmcnt(0)" ::: "memory");
        __builtin_amdgcn_s_barrier();
    };

    // ---- prologue: stage tile 0
    stageA(lds, 0);
    stageB(lds, 0);
    asm volatile("s_waitcnt vmcnt(0)" ::: "memory");
    __builtin_amdgcn_s_barrier();

    // ---- main loop: 16 K-tiles, 2 per trip (static buffer pointers)
    for (int t2 = 0; t2 < 8; ++t2) {
        const int kOdd  = (2 * t2 + 1) * 64;
        const int kEven = (2 * t2 + 2) * 64;
        const bool more = (t2 < 7);
        // even tile from buf0, prefetch odd tile into buf1
        phase(lds, 0, true,  false, lds + BUFSZ, kOdd, false);
        phase(lds, 1, false, true,  lds + BUFSZ, kOdd, true);
        // odd tile from buf1, prefetch next even tile into buf0
        phase(lds + BUFSZ, 0, more,  false, lds, kEven, false);
        phase(lds + BUFSZ, 1, false, more,  lds, kEven, true);
    }

    // ---- epilogue: gate math
    const int rquad = (lane >> 4) * 4;
    #pragma unroll
    for (int mf = 0; mf < 4; ++mf) {
        #pragma unroll
        for (int nf = 0; nf < 2; ++nf) {
            int col = colBase + wc * 32 + nf * 16 + l16;
            float bfv = bfp[col], biv = bip[col], bhv = bhp[col];
            #pragma unroll
            for (int r = 0; r < 4; ++r) {
                int row = rowBase + wr * 64 + mf * 16 + rquad + r;
                float zf = acc[0][mf][nf][r] + bfv;
                float zi = acc[1][mf][nf][r] + biv;
                float zh = acc[2][mf][nf][r] + bhv;
                float fg = 1.f / (1.f + __expf(-zf));
                float ig = 1.f / (1.f + __expf(-zi));
                float gs = fg + ig + EPSF;
                size_t idxo = (size_t)row * Hn + col;
                lr_out[idxo] = __logf(fg / gs + EPSF);
                m_out[idxo]  = (ig / gs) * zh;
            }
        }
    }
}

// ---------------------------------------------------------------------------
// FALLBACK GEMM (fused fp32->bf16 staging) — used if ws too small
// ---------------------------------------------------------------------------
__global__ __launch_bounds__(256) void gate_gemm(
    const float* __restrict__ X,
    const float* __restrict__ Wf, const float* __restrict__ bfp,
    const float* __restrict__ Wi, const float* __restrict__ bip,
    const float* __restrict__ Wh, const float* __restrict__ bhp,
    float* __restrict__ lr_out, float* __restrict__ m_out)
{
    constexpr int BM = 128, BN = 64, BK = 32;
    __shared__ unsigned short Alds[BM * BK];
    __shared__ unsigned short Blds[3][BN * BK];

    const int tid  = threadIdx.x;
    const int lane = tid & 63;
    const int wid  = tid >> 6;
    const int wr   = wid >> 1;
    const int wc   = wid & 1;

    const int tn = blockIdx.x & 15;
    const int tm = blockIdx.x >> 4;
    const int rowBase = tm * BM;
    const int colBase = tn * BN;

    f32x4 acc[3][4][2] = {};
    const float* Wg[3] = {Wf, Wi, Wh};

    for (int k0 = 0; k0 < Dn; k0 += BK) {
        #pragma unroll
        for (int i = 0; i < 4; ++i) {
            int li = tid + 256 * i;
            int r  = li >> 3;
            int c  = (li & 7) << 2;
            const float4 v = *(const float4*)(X + (size_t)(rowBase + r) * Dn + k0 + c);
            ushort4 hv;
            hv.x = f2bf(v.x); hv.y = f2bf(v.y); hv.z = f2bf(v.z); hv.w = f2bf(v.w);
            *(ushort4*)(&Alds[r * BK + c]) = hv;
        }
        #pragma unroll
        for (int g = 0; g < 3; ++g) {
            #pragma unroll
            for (int i = 0; i < 2; ++i) {
                int li = tid + 256 * i;
                int r  = li >> 3;
                int c  = (li & 7) << 2;
                const float4 v = *(const float4*)(Wg[g] + (size_t)(colBase + r) * Dn + k0 + c);
                ushort4 hv;
                hv.x = f2bf(v.x); hv.y = f2bf(v.y); hv.z = f2bf(v.z); hv.w = f2bf(v.w);
                *(ushort4*)(&Blds[g][r * BK + c]) = hv;
            }
        }
        __syncthreads();

        const int kq  = (lane >> 4) << 3;
        const int l16 = lane & 15;
        s16x8 af[4];
        #pragma unroll
        for (int mf = 0; mf < 4; ++mf) {
            int row = wr * 64 + mf * 16 + l16;
            af[mf] = *(const s16x8*)(&Alds[row * BK + kq]);
        }
        #pragma unroll
        for (int g = 0; g < 3; ++g) {
            s16x8 bfr[2];
            #pragma unroll
            for (int nf = 0; nf < 2; ++nf) {
                int col = wc * 32 + nf * 16 + l16;
                bfr[nf] = *(const s16x8*)(&Blds[g][col * BK + kq]);
            }
            #pragma unroll
            for (int mf = 0; mf < 4; ++mf)
                #pragma unroll
                for (int nf = 0; nf < 2; ++nf)
                    acc[g][mf][nf] = __builtin_amdgcn_mfma_f32_16x16x32_bf16(
                        af[mf], bfr[nf], acc[g][mf][nf], 0, 0, 0);
        }
        __syncthreads();
    }

    const int l16   = lane & 15;
    const int rquad = (lane >> 4) * 4;
    #pragma unroll
    for (int mf = 0; mf < 4; ++mf) {
        #pragma unroll
        for (int nf = 0; nf < 2; ++nf) {
            int col = colBase + wc * 32 + nf * 16 + l16;
            float bfv = bfp[col], biv = bip[col], bhv = bhp[col];
            #pragma unroll
            for (int r = 0; r < 4; ++r) {
                int row = rowBase + wr * 64 + mf * 16 + rquad + r;
                float zf = acc[0][mf][nf][r] + bfv;
                float zi = acc[1][mf][nf][r] + biv;
                float zh = acc[2][mf][nf][r] + bhv;
                float fg = 1.f / (1.f + __expf(-zf));
                float ig = 1.f / (1.f + __expf(-zi));
                float gs = fg + ig + EPSF;
                size_t idx = (size_t)row * Hn + col;
                lr_out[idx] = __logf(fg / gs + EPSF);
                m_out[idx]  = (ig / gs) * zh;
            }
        }
    }
}

// ---------------------------------------------------------------------------
// Chunked scan, pass 1
// ---------------------------------------------------------------------------
__global__ __launch_bounds__(256) void scan_chunks(
    const float* __restrict__ lr, const float* __restrict__ m,
    float* __restrict__ lcA, float* __restrict__ ccA)
{
    int g  = blockIdx.x * 256 + threadIdx.x;
    int h  = g & 1023;
    int bc = g >> 10;
    int b  = bc & 7;
    int c  = bc >> 3;
    const size_t base = ((size_t)b * Sn + (size_t)c * CH) * Hn + h;

    float s = 0.f, cc = 0.f;
    #pragma unroll 4
    for (int t = CH - 1; t >= 0; --t) {
        s += lr[base + (size_t)t * Hn];
        cc += __expf(s) * m[base + (size_t)t * Hn];
    }
    int o = c * (Bn * Hn) + b * Hn + h;
    lcA[o] = s;
    ccA[o] = cc;
}

// ---------------------------------------------------------------------------
// Chunked scan, pass 2
// ---------------------------------------------------------------------------
__global__ __launch_bounds__(256) void scan_apply(
    const float* __restrict__ lr, float* __restrict__ io,
    const float* __restrict__ h0,
    const float* __restrict__ lcA, const float* __restrict__ ccA)
{
    int g  = blockIdx.x * 256 + threadIdx.x;
    int h  = g & 1023;
    int bc = g >> 10;
    int b  = bc & 7;
    int c  = bc >> 3;
    const int bh = b * Hn + h;

    float lcv[NC], ccv[NC], pref[NC];
    #pragma unroll
    for (int j = 0; j < NC; ++j) {
        lcv[j] = lcA[j * (Bn * Hn) + bh];
        ccv[j] = ccA[j * (Bn * Hn) + bh];
    }
    float run = 0.f;
    #pragma unroll
    for (int j = 0; j < NC; ++j) { run += lcv[j]; pref[j] = run; }
    const float Ltot = run;

    float Lpre = 0.f, acc = 0.f;
    #pragma unroll
    for (int j = 0; j < NC; ++j) {
        if (j < c) {
            Lpre += lcv[j];
            acc  += __expf(Ltot - pref[j]) * ccv[j];
        }
    }

    const float h0v = h0[bh];
    const size_t base = ((size_t)b * Sn + (size_t)c * CH) * Hn + h;
    float L = Lpre;
    #pragma unroll 4
    for (int t = 0; t < CH; ++t) {
        float mv = io[base + (size_t)t * Hn];
        float lv = lr[base + (size_t)t * Hn];
        acc += __expf(Ltot - L) * mv;   // L = L_{t-1}
        L += lv;
        io[base + (size_t)t * Hn] = acc + __expf(L) * h0v;
    }
}

// ---------------------------------------------------------------------------
// FALLBACK scan
// ---------------------------------------------------------------------------
__global__ __launch_bounds__(64) void scan_kernel(
    const float* __restrict__ lr, float* __restrict__ io,
    const float* __restrict__ h0)
{
    const int tid = blockIdx.x * 64 + threadIdx.x;
    const int b  = tid >> 10;
    const int hh = tid & 1023;
    const float* lrp = lr + (size_t)b * Sn * Hn + hh;
    float*       iop = io + (size_t)b * Sn * Hn + hh;

    float Lt = 0.f;
    #pragma unroll 8
    for (int t = 0; t < Sn; ++t) Lt += lrp[(size_t)t * Hn];

    float L = 0.f, acc = 0.f;
    const float h0v = h0[tid];
    #pragma unroll 4
    for (int t = 0; t < Sn; ++t) {
        float mv = iop[(size_t)t * Hn];
        float lv = lrp[(size_t)t * Hn];
        acc += __expf(Lt - L) * mv;
        L += lv;
        iop[(size_t)t * Hn] = acc + __expf(L) * h0v;
    }
}

extern "C" void kernel_launch(void* const* d_in, const int* in_sizes, int n_in,
                              void* d_out, int out_size, void* d_ws, size_t ws_size,
                              hipStream_t stream)
{
    const float* X  = (const float*)d_in[0];
    const float* h0 = (const float*)d_in[1];
    const float* Wf = (const float*)d_in[2];
    const float* bf = (const float*)d_in[3];
    const float* Wi = (const float*)d_in[4];
    const float* bi = (const float*)d_in[5];
    const float* Wh = (const float*)d_in[6];
    const float* bh = (const float*)d_in[7];
    float* out = (float*)d_out;

    char*  base = (char*)d_ws;
    float* lr   = (float*)d_ws;                       // 64 MB
    const size_t szLR = (size_t)Mn * Hn * 4;          // 64 MB
    const size_t szX  = (size_t)Mn * Dn * 2;          // 32 MB
    const size_t szW  = (size_t)3 * Hn * Dn * 2;      // 6 MB
    const size_t szC  = (size_t)2 * NC * Bn * Hn * 4; // 1 MB

    const bool fastgemm = ws_size >= szLR + szX + szW + szC;
    const bool fastscan = fastgemm || (ws_size >= szLR + szC);

    if (fastgemm) {
        unsigned short* Xb = (unsigned short*)(base + szLR);
        unsigned short* Wb = (unsigned short*)(base + szLR + szX);
        cvt_bf16<<<(Mn * Dn / 8) / 256, 256, 0, stream>>>(X, Xb, Mn * Dn / 8);
        cvt_w3<<<(3 * Hn * Dn / 8) / 256, 256, 0, stream>>>(Wf, Wi, Wh, Wb);
        const int grid = (Mn / 256) * (Hn / 64);   // 1024 blocks
        gate_gemm_bf<<<grid, 512, 0, stream>>>(Xb, Wb, bf, bi, bh, lr, out);
    } else {
        const int grid = (Mn / 128) * (Hn / 64);   // 2048 blocks
        gate_gemm<<<grid, 256, 0, stream>>>(X, Wf, bf, Wi, bi, Wh, bh, lr, out);
    }

    if (fastscan) {
        float* chunkBase = (float*)(base + (fastgemm ? szLR + szX + szW : szLR));
        float* lcA = chunkBase;
        float* ccA = chunkBase + (size_t)NC * Bn * Hn;
        scan_chunks<<<(Bn * Hn * NC) / 256, 256, 0, stream>>>(lr, out, lcA, ccA);
        scan_apply<<<(Bn * Hn * NC) / 256, 256, 0, stream>>>(lr, out, h0, lcA, ccA);
    } else {
        scan_kernel<<<(Bn * Hn) / 64, 64, 0, stream>>>(lr, out, h0);
    }
}